// Round 1
// baseline (249.366 us; speedup 1.0000x reference)
//
#include <hip/hip_runtime.h>

#define NB 65536

typedef __attribute__((ext_vector_type(8))) short bf16x8;
typedef __attribute__((ext_vector_type(4))) float f32x4;

__device__ __forceinline__ unsigned short f2bf(float f) {
  union { float f; unsigned u; } v; v.f = f;
  return (unsigned short)((v.u + 0x7FFFu + ((v.u >> 16) & 1u)) >> 16);
}

// ws layout (bf16 element offsets)
#define OFF_A1 0
#define OFF_B1 65536
#define OFF_C1 98304
#define OFF_D1 163840
#define OFF_A2 196608
#define OFF_B2 262144
#define OFF_C2 327680
#define OFF_D2 360448
#define OFF_W1 393216
#define OFF_W2 655360
#define W_TOTAL 917504

struct WPtrs { const float* p[10]; };

__global__ void convert_weights(WPtrs wp, unsigned short* __restrict__ dst) {
  const int off[11] = {OFF_A1, OFF_B1, OFF_C1, OFF_D1, OFF_A2, OFF_B2,
                       OFF_C2, OFF_D2, OFF_W1, OFF_W2, W_TOTAL};
  int gid4 = (blockIdx.x * blockDim.x + threadIdx.x) * 4;
  if (gid4 >= W_TOTAL) return;
  int seg = 0;
  #pragma unroll
  for (int i = 1; i < 10; ++i) seg += (gid4 >= off[i]) ? 1 : 0;
  const float4 f = *(const float4*)(wp.p[seg] + (gid4 - off[seg]));
  ushort4 h;
  h.x = f2bf(f.x); h.y = f2bf(f.y); h.z = f2bf(f.z); h.w = f2bf(f.w);
  *(ushort4*)(dst + gid4) = h;
}

#define MFMA16(acc, a, b) \
  acc = __builtin_amdgcn_mfma_f32_16x16x32_bf16(a, b, acc, 0, 0, 0)

// LDS geometry (bf16 elems). Padded strides: +8 bf16 keeps 16B row alignment
// and advances 4 banks/row -> <=2-way aliasing on ds_read_b128 (free, m136).
#define CLD 72    // chunk [128][72]   (64 used)  -> 18432 B
#define VLD 264   // vbuf  [128][264]  (256 used) -> 67584 B  (v, then w)
#define HLD 136   // hbuf  [128][136]  (128 used) -> 34816 B
#define SMEM_BYTES (18432 + 67584 + 34816)

__global__ __launch_bounds__(512, 2) void wh_fused(
    const float* __restrict__ s1, const float* __restrict__ s2,
    const float* __restrict__ u, const unsigned short* __restrict__ wbf,
    const float* __restrict__ b1, const float* __restrict__ b2,
    float* __restrict__ out)
{
  extern __shared__ char smem[];
  unsigned short* chunk = (unsigned short*)smem;                    // [128][72]
  unsigned short* vbuf  = (unsigned short*)(smem + 18432);          // [128][264]
  unsigned short* hbuf  = (unsigned short*)(smem + 18432 + 67584);  // [128][136]

  const int t   = threadIdx.x;
  const int wid = t >> 6;     // wave 0..7 = column group
  const int lid = t & 63;
  const int lr  = lid & 15;   // A-row / B-col / D-col index
  const int lg  = lid >> 4;   // k-group / D row-group
  const int row0 = blockIdx.x * 128;

  // --- stage a [128 x 64] fp32 panel -> bf16 chunk LDS ---
  auto stage = [&](const float* __restrict__ src, int sld, int c0) {
    const int cg = t & 15;        // 4-float col group
    const int r0 = t >> 4;        // 0..31
    #pragma unroll
    for (int rr = 0; rr < 128; rr += 32) {
      const float4 f = *(const float4*)(src + (size_t)(row0 + r0 + rr) * sld + c0 + cg * 4);
      ushort4 h;
      h.x = f2bf(f.x); h.y = f2bf(f.y); h.z = f2bf(f.z); h.w = f2bf(f.w);
      *(ushort4*)(chunk + (r0 + rr) * CLD + cg * 4) = h;
    }
  };

  // A fragment from LDS: X[m*16+lr][kk + lg*8 .. +7]
  auto ldsA = [&](const unsigned short* buf, int ld, int m, int kk) -> bf16x8 {
    return *(const bf16x8*)(buf + (m * 16 + lr) * ld + kk + lg * 8);
  };
  // B fragment from global row-major W: W[nrow+lr][kk + lg*8 .. +7]
  auto ldgB = [&](const unsigned short* w, int ld, int nrow, int kk) -> bf16x8 {
    return *(const bf16x8*)(w + (size_t)(nrow + lr) * ld + kk + lg * 8);
  };

  // ================= Phase A: ns1 = [s1|u]@[A1|B1]^T, v = [s1|u]@[C1|D1]^T
  f32x4 ns1[8][2] = {};
  f32x4 vac[8][2] = {};
  for (int c = 0; c < 6; ++c) {
    __syncthreads();
    if (c < 4) stage(s1, 256, c * 64); else stage(u, 128, (c - 4) * 64);
    __syncthreads();
    const unsigned short* WA = wbf + (c < 4 ? OFF_A1 : OFF_B1);
    const unsigned short* WC = wbf + (c < 4 ? OFF_C1 : OFF_D1);
    const int wld   = (c < 4) ? 256 : 128;
    const int kbase = (c < 4) ? c * 64 : (c - 4) * 64;
    #pragma unroll
    for (int k2 = 0; k2 < 2; ++k2) {
      bf16x8 a[8];
      #pragma unroll
      for (int m = 0; m < 8; ++m) a[m] = ldsA(chunk, CLD, m, k2 * 32);
      #pragma unroll
      for (int n = 0; n < 2; ++n) {
        bf16x8 ba = ldgB(WA, wld, wid * 32 + n * 16, kbase + k2 * 32);
        bf16x8 bc = ldgB(WC, wld, wid * 32 + n * 16, kbase + k2 * 32);
        #pragma unroll
        for (int m = 0; m < 8; ++m) {
          MFMA16(ns1[m][n], a[m], ba);
          MFMA16(vac[m][n], a[m], bc);
        }
      }
    }
  }
  // store ns1 (output 0), write v -> vbuf (bf16)
  #pragma unroll
  for (int m = 0; m < 8; ++m)
    #pragma unroll
    for (int n = 0; n < 2; ++n)
      #pragma unroll
      for (int i = 0; i < 4; ++i)
        out[(size_t)(row0 + m * 16 + lg * 4 + i) * 256 + wid * 32 + n * 16 + lr] = ns1[m][n][i];
  #pragma unroll
  for (int m = 0; m < 8; ++m)
    #pragma unroll
    for (int n = 0; n < 2; ++n)
      #pragma unroll
      for (int i = 0; i < 4; ++i)
        vbuf[(m * 16 + lg * 4 + i) * VLD + wid * 32 + n * 16 + lr] = f2bf(vac[m][n][i]);
  __syncthreads();

  // ================= Phase B: w = tanh(v@W1^T + b1) @ W2^T + b2
  f32x4 wac[8][2] = {};
  for (int hc = 0; hc < 8; ++hc) {
    f32x4 hac[8] = {};
    for (int k = 0; k < 8; ++k) {
      bf16x8 a[8];
      #pragma unroll
      for (int m = 0; m < 8; ++m) a[m] = ldsA(vbuf, VLD, m, k * 32);
      bf16x8 bw = ldgB(wbf + OFF_W1, 256, hc * 128 + wid * 16, k * 32);
      #pragma unroll
      for (int m = 0; m < 8; ++m) MFMA16(hac[m], a[m], bw);
    }
    const float bias1 = b1[hc * 128 + wid * 16 + lr];
    __syncthreads();   // previous chunk's hbuf reads complete
    #pragma unroll
    for (int m = 0; m < 8; ++m)
      #pragma unroll
      for (int i = 0; i < 4; ++i)
        hbuf[(m * 16 + lg * 4 + i) * HLD + wid * 16 + lr] = f2bf(tanhf(hac[m][i] + bias1));
    __syncthreads();   // hbuf writes visible
    for (int k = 0; k < 4; ++k) {
      bf16x8 a[8];
      #pragma unroll
      for (int m = 0; m < 8; ++m) a[m] = ldsA(hbuf, HLD, m, k * 32);
      #pragma unroll
      for (int n = 0; n < 2; ++n) {
        bf16x8 b2f = ldgB(wbf + OFF_W2, 1024, wid * 32 + n * 16, hc * 128 + k * 32);
        #pragma unroll
        for (int m = 0; m < 8; ++m) MFMA16(wac[m][n], a[m], b2f);
      }
    }
  }
  // w (+b2) -> vbuf (bf16); safe: all vbuf reads precede the last mid-chunk barrier
  #pragma unroll
  for (int m = 0; m < 8; ++m)
    #pragma unroll
    for (int n = 0; n < 2; ++n) {
      const float bias2 = b2[wid * 32 + n * 16 + lr];
      #pragma unroll
      for (int i = 0; i < 4; ++i)
        vbuf[(m * 16 + lg * 4 + i) * VLD + wid * 32 + n * 16 + lr] = f2bf(wac[m][n][i] + bias2);
    }
  __syncthreads();

  // ================= Phase C: ns2 = s2@A2^T + w@B2^T ; y = s2@C2^T + w@D2^T
  f32x4 ns2[8][2] = {};
  f32x4 yac[8] = {};
  for (int c = 0; c < 4; ++c) {
    __syncthreads();
    stage(s2, 256, c * 64);
    __syncthreads();
    #pragma unroll
    for (int k2 = 0; k2 < 2; ++k2) {
      bf16x8 a[8];
      #pragma unroll
      for (int m = 0; m < 8; ++m) a[m] = ldsA(chunk, CLD, m, k2 * 32);
      const int kk = c * 64 + k2 * 32;
      bf16x8 by = ldgB(wbf + OFF_C2, 256, wid * 16, kk);
      #pragma unroll
      for (int n = 0; n < 2; ++n) {
        bf16x8 ba = ldgB(wbf + OFF_A2, 256, wid * 32 + n * 16, kk);
        #pragma unroll
        for (int m = 0; m < 8; ++m) MFMA16(ns2[m][n], a[m], ba);
      }
      #pragma unroll
      for (int m = 0; m < 8; ++m) MFMA16(yac[m], a[m], by);
    }
  }
  for (int k = 0; k < 8; ++k) {   // w part (A from vbuf)
    bf16x8 a[8];
    #pragma unroll
    for (int m = 0; m < 8; ++m) a[m] = ldsA(vbuf, VLD, m, k * 32);
    bf16x8 by = ldgB(wbf + OFF_D2, 256, wid * 16, k * 32);
    #pragma unroll
    for (int n = 0; n < 2; ++n) {
      bf16x8 bb = ldgB(wbf + OFF_B2, 256, wid * 32 + n * 16, k * 32);
      #pragma unroll
      for (int m = 0; m < 8; ++m) MFMA16(ns2[m][n], a[m], bb);
    }
    #pragma unroll
    for (int m = 0; m < 8; ++m) MFMA16(yac[m], a[m], by);
  }
  float* out2 = out + (size_t)NB * 256;
  float* outy = out + (size_t)NB * 512;
  #pragma unroll
  for (int m = 0; m < 8; ++m)
    #pragma unroll
    for (int n = 0; n < 2; ++n)
      #pragma unroll
      for (int i = 0; i < 4; ++i)
        out2[(size_t)(row0 + m * 16 + lg * 4 + i) * 256 + wid * 32 + n * 16 + lr] = ns2[m][n][i];
  #pragma unroll
  for (int m = 0; m < 8; ++m)
    #pragma unroll
    for (int i = 0; i < 4; ++i)
      outy[(size_t)(row0 + m * 16 + lg * 4 + i) * 128 + wid * 16 + lr] = yac[m][i];
}

extern "C" void kernel_launch(void* const* d_in, const int* in_sizes, int n_in,
                              void* d_out, int out_size, void* d_ws, size_t ws_size,
                              hipStream_t stream) {
  const float* s1 = (const float*)d_in[0];
  const float* s2 = (const float*)d_in[1];
  const float* u  = (const float*)d_in[2];
  WPtrs wp;
  wp.p[0] = (const float*)d_in[3];   // A1
  wp.p[1] = (const float*)d_in[4];   // B1
  wp.p[2] = (const float*)d_in[5];   // C1
  wp.p[3] = (const float*)d_in[6];   // D1
  wp.p[4] = (const float*)d_in[7];   // A2
  wp.p[5] = (const float*)d_in[8];   // B2
  wp.p[6] = (const float*)d_in[9];   // C2
  wp.p[7] = (const float*)d_in[10];  // D2
  wp.p[8] = (const float*)d_in[11];  // W1
  wp.p[9] = (const float*)d_in[13];  // W2
  const float* b1 = (const float*)d_in[12];
  const float* b2 = (const float*)d_in[14];
  unsigned short* wbf = (unsigned short*)d_ws;

  convert_weights<<<dim3((W_TOTAL / 4 + 511) / 512), dim3(512), 0, stream>>>(wp, wbf);
  wh_fused<<<dim3(NB / 128), dim3(512), SMEM_BYTES, stream>>>(
      s1, s2, u, wbf, b1, b2, (float*)d_out);
}